// Round 1
// baseline (3551.896 us; speedup 1.0000x reference)
//
#include <hip/hip_runtime.h>
#include <hip/hip_bf16.h>

// Problem constants
#define BB 16
#define TT 16
#define CC 128
#define HW 1024           // 32*32
#define PIX (CC*HW)       // per-batch per-state floats = 131072

__device__ __forceinline__ float sigf(float x) { return 1.0f / (1.0f + expf(-x)); }

// out[b][M][1024] = W[M x K] * act[b][K][1024] + bias
// act: k<128 -> A0 + b*sA0 + k*1024 ; k>=128 -> A1 + b*sA1 + (k-128)*1024
__global__ __launch_bounds__(256) void gemm_conv(
    const float* __restrict__ W, const float* __restrict__ bias,
    const float* __restrict__ A0, long sA0,
    const float* __restrict__ A1, long sA1,
    float* __restrict__ out, int M, int K)
{
    __shared__ __align__(16) float Ws[16][64];
    __shared__ __align__(16) float As[16][64];

    const int b  = blockIdx.z;
    const int n0 = blockIdx.x * 64;
    const int m0 = blockIdx.y * 64;
    const int tid = threadIdx.x;
    const int tx = tid & 15;      // pixel sub-tile
    const int ty = tid >> 4;      // row sub-tile

    const float* A0b = A0 + (long)b * sA0;
    const float* A1b = A1 ? (A1 + (long)b * sA1) : nullptr;

    float acc[4][4] = {};

    for (int k0 = 0; k0 < K; k0 += 16) {
        // stage W tile (64 rows x 16 k), transposed into Ws[k][row]
        {
            const int row = tid >> 2;          // 0..63
            const int kk  = (tid & 3) * 4;     // 0,4,8,12
            const float4 w4 = *(const float4*)(W + (long)(m0 + row) * K + k0 + kk);
            Ws[kk + 0][row] = w4.x;
            Ws[kk + 1][row] = w4.y;
            Ws[kk + 2][row] = w4.z;
            Ws[kk + 3][row] = w4.w;
        }
        // stage act tile (16 k x 64 pixels)
        {
            const int kk  = tid >> 4;          // 0..15
            const int col = (tid & 15) * 4;    // 0..60
            const int k = k0 + kk;
            const float* src = (k < 128) ? (A0b + (long)k * HW)
                                         : (A1b + (long)(k - 128) * HW);
            *(float4*)&As[kk][col] = *(const float4*)(src + n0 + col);
        }
        __syncthreads();
        #pragma unroll
        for (int kk = 0; kk < 16; ++kk) {
            const float4 a4 = *(const float4*)&Ws[kk][ty * 4];
            const float4 b4 = *(const float4*)&As[kk][tx * 4];
            const float av[4] = {a4.x, a4.y, a4.z, a4.w};
            const float bv[4] = {b4.x, b4.y, b4.z, b4.w};
            #pragma unroll
            for (int i = 0; i < 4; ++i)
                #pragma unroll
                for (int j = 0; j < 4; ++j)
                    acc[i][j] += av[i] * bv[j];
        }
        __syncthreads();
    }

    #pragma unroll
    for (int i = 0; i < 4; ++i) {
        const int row = m0 + ty * 4 + i;
        const float bb = bias[row];
        float4 o;
        o.x = acc[i][0] + bb;
        o.y = acc[i][1] + bb;
        o.z = acc[i][2] + bb;
        o.w = acc[i][3] + bb;
        *(float4*)(out + ((long)b * M + row) * HW + n0 + tx * 4) = o;
    }
}

// gates [16][512][1024]: 0-127 a_xh(sig), 128-255 ga(sig), 256-383 gv(tanh), 384-511 a_xh1(sig)
__global__ __launch_bounds__(256) void lstm_update(
    const float* __restrict__ gates, float* __restrict__ Cst, float* __restrict__ H)
{
    const long idx = (long)blockIdx.x * 256 + threadIdx.x;   // over 2M
    const int p = idx & 1023;
    const int c = (idx >> 10) & 127;
    const int b = idx >> 17;
    const float* gb = gates + (long)b * 512 * HW;
    const float g0 = gb[(long)(c)       * HW + p];
    const float g1 = gb[(long)(128 + c) * HW + p];
    const float g2 = gb[(long)(256 + c) * HW + p];
    const float g3 = gb[(long)(384 + c) * HW + p];
    const float a   = sigf(g0);
    const float ga  = sigf(g1);
    const float gv  = tanhf(g2);
    const float a1  = sigf(g3);
    const float cc = Cst[idx] * a + ga * gv;
    Cst[idx] = cc;
    H[idx] = a1 * tanhf(cc);
}

// vkq [16][384][1024]: vh 0-127, kh 128-255, qh' 256-383 ; kmvm [16][256][1024]: km, vm
// zhzm [16][256][1024]: zh 0-127, zm 128-255
__global__ __launch_bounds__(256) void attn_kernel(
    const float* __restrict__ vkq, const float* __restrict__ kmvm, float* __restrict__ zhzm)
{
    const int lane = threadIdx.x & 31;      // j
    const int rloc = threadIdx.x >> 5;      // 0..7
    const int R = blockIdx.x * 8 + rloc;    // row id over B*C*32 = 65536
    const int i = R & 31;
    const int c = (R >> 5) & 127;
    const int b = R >> 12;
    const long base3 = ((long)b * 384 + c) * HW;
    const long base2 = ((long)b * 256 + c) * HW;
    const int j = lane;

    const float vh  = vkq[base3 + i * 32 + j];
    const float kh  = vkq[base3 + 128 * HW + i * 32 + j];
    const float qhT = vkq[base3 + 256 * HW + j * 32 + i];   // spatial transpose
    const float km  = kmvm[base2 + i * 32 + j];
    const float vm  = kmvm[base2 + 128 * HW + i * 32 + j];

    float sh = kh * qhT;
    float sm = qhT * km;
    float mh = sh, mm = sm;
    #pragma unroll
    for (int o = 16; o > 0; o >>= 1) {
        mh = fmaxf(mh, __shfl_xor(mh, o, 32));
        mm = fmaxf(mm, __shfl_xor(mm, o, 32));
    }
    const float eh = expf(sh - mh);
    const float em = expf(sm - mm);
    float s1 = eh, s2 = em;
    #pragma unroll
    for (int o = 16; o > 0; o >>= 1) {
        s1 += __shfl_xor(s1, o, 32);
        s2 += __shfl_xor(s2, o, 32);
    }
    zhzm[base2 + i * 32 + j]            = vh * (eh / s1);
    zhzm[base2 + 128 * HW + i * 32 + j] = vm * (em / s2);
}

// ogi [16][384][1024]: ot(sig) 0-127, gt(tanh) 128-255, it(sig) 256-383
__global__ __launch_bounds__(256) void final_update(
    const float* __restrict__ ogi, float* __restrict__ m, float* __restrict__ H)
{
    const long idx = (long)blockIdx.x * 256 + threadIdx.x;
    const int p = idx & 1023;
    const int c = (idx >> 10) & 127;
    const int b = idx >> 17;
    const float* gb = ogi + (long)b * 384 * HW;
    const float ot = sigf(gb[(long)(c)       * HW + p]);
    const float gt = tanhf(gb[(long)(128 + c) * HW + p]);
    const float it = sigf(gb[(long)(256 + c) * HW + p]);
    const float mn = gt * it + (1.0f - it) * m[idx];
    m[idx] = mn;
    H[idx] = ot * mn;
}

extern "C" void kernel_launch(void* const* d_in, const int* in_sizes, int n_in,
                              void* d_out, int out_size, void* d_ws, size_t ws_size,
                              hipStream_t stream)
{
    const float* x  = (const float*)d_in[0];   // [16][16][128][1024]
    const float* c0 = (const float*)d_in[1];   // [16][128][1024]
    const float* W5 = (const float*)d_in[2];   // [5][128][128]
    const float* b5 = (const float*)d_in[3];   // [5][128]
    const float* W8 = (const float*)d_in[4];   // [8][128][256]
    const float* b8 = (const float*)d_in[5];   // [8][128]
    float* out = (float*)d_out;

    const long S = (long)BB * PIX;             // 2M floats per state tensor
    float* ws   = (float*)d_ws;
    float* H    = ws;                          // 2M
    float* m    = H + S;                       // 2M
    float* Cst  = m + S;                       // 2M
    float* R    = Cst + S;                     // scratch region, 14M floats
    float* gates = R;                          // 8M  [16][512][1024]
    float* vkq   = R;                          // 6M  [16][384][1024]
    float* kmvm  = R + 6 * S;                  // 4M  [16][256][1024]
    float* zhzm  = R + 10 * S;                 // 4M  [16][256][1024]
    float* z     = R;                          // 2M  [16][128][1024]
    float* ogi   = R + 2 * S;                  // 6M  [16][384][1024]

    hipMemsetAsync(H, 0, S * sizeof(float), stream);
    hipMemsetAsync(m, 0, S * sizeof(float), stream);
    hipMemcpyAsync(Cst, c0, S * sizeof(float), hipMemcpyDeviceToDevice, stream);

    const dim3 blk(256);
    for (int t = 0; t < TT; ++t) {
        const float* xt = x + (long)t * PIX;   // batch stride = TT*PIX

        // gates = W8[4..7] * [H ; x_t] + b8[4..7]   (M=512, K=256)
        gemm_conv<<<dim3(16, 8, 16), blk, 0, stream>>>(
            W8 + 4l * CC * 256, b8 + 4 * CC, H, PIX, xt, (long)TT * PIX, gates, 512, 256);
        lstm_update<<<8192, blk, 0, stream>>>(gates, Cst, H);

        // vh,kh,qh = W5[0..2] * H   (M=384, K=128)
        gemm_conv<<<dim3(16, 6, 16), blk, 0, stream>>>(
            W5, b5, H, PIX, nullptr, 0, vkq, 384, 128);
        // km,vm = W5[3..4] * m      (M=256, K=128)
        gemm_conv<<<dim3(16, 4, 16), blk, 0, stream>>>(
            W5 + 3l * CC * CC, b5 + 3 * CC, m, PIX, nullptr, 0, kmvm, 256, 128);

        attn_kernel<<<8192, blk, 0, stream>>>(vkq, kmvm, zhzm);

        // z = W8[0] * [zh ; zm]     (M=128, K=256)
        gemm_conv<<<dim3(16, 2, 16), blk, 0, stream>>>(
            W8, b8, zhzm, 2l * PIX, zhzm + PIX, 2l * PIX, z, 128, 256);
        // ot,gt,it = W8[1..3] * [H ; z]  (M=384, K=256)
        gemm_conv<<<dim3(16, 6, 16), blk, 0, stream>>>(
            W8 + 1l * CC * 256, b8 + CC, H, PIX, z, PIX, ogi, 384, 256);

        final_update<<<8192, blk, 0, stream>>>(ogi, m, H);
    }

    hipMemcpyAsync(out, H, S * sizeof(float), hipMemcpyDeviceToDevice, stream);
}

// Round 2
// 1986.288 us; speedup vs baseline: 1.7882x; 1.7882x over previous
//
#include <hip/hip_runtime.h>
#include <hip/hip_bf16.h>

#define BB 16
#define TT 16
#define CC 128
#define HW 1024           // 32*32
#define PIX (CC*HW)       // 131072 elems per [b][128][1024] tensor slice... per batch
#define STOT ((long)BB*PIX) // 2M elems per state tensor

typedef short short8 __attribute__((ext_vector_type(8)));
typedef float f32x4  __attribute__((ext_vector_type(4)));

__device__ __forceinline__ float sigf(float x) { return 1.0f / (1.0f + expf(-x)); }

// ---- packed hi/lo bf16 format: uint32 = (bf16(x)<<16) | bf16(x - bf16(x)) ----
__device__ __forceinline__ unsigned pack_hl(float x) {
    unsigned u = __float_as_uint(x);
    unsigned hi = (u + 0x7fffu + ((u >> 16) & 1u)) >> 16;          // RNE to bf16
    float r = x - __uint_as_float(hi << 16);
    unsigned v = __float_as_uint(r);
    unsigned lo = (v + 0x7fffu + ((v >> 16) & 1u)) >> 16;
    return (hi << 16) | lo;
}
__device__ __forceinline__ float unpack_hl(unsigned p) {
    return __uint_as_float(p & 0xffff0000u) + __uint_as_float(p << 16);
}

// 8 packed words -> hi-frag + lo-frag (short8 = 8 bf16)
__device__ __forceinline__ void split_frag(uint4 a, uint4 b, short8& hi, short8& lo) {
    unsigned w[8] = {a.x, a.y, a.z, a.w, b.x, b.y, b.z, b.w};
    union U { unsigned u[4]; short8 s; } h, l;
    #pragma unroll
    for (int j = 0; j < 4; ++j) {
        h.u[j] = (w[2*j] >> 16)      | (w[2*j+1] & 0xffff0000u);
        l.u[j] = (w[2*j] & 0xffffu)  | (w[2*j+1] << 16);
    }
    hi = h.s; lo = l.s;
}

// LDS tile: 128 rows x 32 k-words, row stride 36 words, quad-XOR swizzle.
// addr(row,k) quad-aligned when k%4==0 -> b128 reads/writes stay 16B aligned.
__device__ __forceinline__ int taddr(int row, int kw) {
    return row * 36 + ((((kw >> 2) + (row >> 2)) & 7) << 2) + (kw & 3);
}

// ---------------- MFMA GEMM ----------------
// out[b][M][1024] = W[M x K] * act[b][K][1024] + bias ; packed inputs.
// B-source select: if m0>=m_split -> actB (kofs 0); else if k>=k_split -> actB (kofs k_split); else actA.
template<bool PACK>
__global__ __launch_bounds__(256, 2) void gemm_mfma(
    const unsigned* __restrict__ Wp, const float* __restrict__ bias,
    const unsigned* __restrict__ actA, long sA,
    const unsigned* __restrict__ actB, long sB,
    int k_split, int m_split,
    void* __restrict__ outv, int M, int K)
{
    __shared__ __align__(16) unsigned Ws[128 * 36];
    __shared__ __align__(16) unsigned Bs[128 * 36];

    const int b  = blockIdx.z;
    const int n0 = blockIdx.x * 128;
    const int m0 = blockIdx.y * 128;
    const int t  = threadIdx.x;
    const int lane = t & 63;
    const int w  = t >> 6;
    const int wm = w & 1, wn = w >> 1;
    const int g  = lane >> 4, pl = lane & 15;

    f32x4 acc[4][4] = {};   // [mt][nt]

    for (int k0 = 0; k0 < K; k0 += 32) {
        // ---- stage A (weights) : direct copy, swizzled ----
        #pragma unroll
        for (int it = 0; it < 4; ++it) {
            int idx = t + 256 * it;
            int row = idx >> 3, kq = idx & 7;
            uint4 v = *(const uint4*)(Wp + (long)(m0 + row) * K + k0 + 4 * kq);
            *(uint4*)(Ws + taddr(row, 4 * kq)) = v;
        }
        // ---- stage B (activations) : register 4x4 transpose -> [pixel][k] ----
        {
            const unsigned* src; int kofs;
            if (m0 >= m_split)      { src = actB + (long)b * sB; kofs = 0; }
            else if (k0 >= k_split) { src = actB + (long)b * sB; kofs = k_split; }
            else                    { src = actA + (long)b * sA; kofs = 0; }
            const int p4 = t & 31, kq = t >> 5;   // kq 0..7
            uint4 v[4];
            #pragma unroll
            for (int i = 0; i < 4; ++i) {
                int kc = k0 + 4 * kq + i - kofs;
                v[i] = *(const uint4*)(src + (long)kc * HW + n0 + 4 * p4);
            }
            #pragma unroll
            for (int j = 0; j < 4; ++j) {
                uint4 wv;
                wv.x = ((const unsigned*)&v[0])[j];
                wv.y = ((const unsigned*)&v[1])[j];
                wv.z = ((const unsigned*)&v[2])[j];
                wv.w = ((const unsigned*)&v[3])[j];
                *(uint4*)(Bs + taddr(4 * p4 + j, 4 * kq)) = wv;
            }
        }
        __syncthreads();

        // ---- fragments + MFMA (3-term split precision) ----
        short8 ahi[4], alo[4], bhi[4], blo[4];
        #pragma unroll
        for (int mt = 0; mt < 4; ++mt) {
            int row = 64 * wm + 16 * mt + pl;
            uint4 w0 = *(const uint4*)(Ws + taddr(row, 8 * g));
            uint4 w1 = *(const uint4*)(Ws + taddr(row, 8 * g + 4));
            split_frag(w0, w1, ahi[mt], alo[mt]);
        }
        #pragma unroll
        for (int nt = 0; nt < 4; ++nt) {
            int prow = 64 * wn + 16 * nt + pl;
            uint4 w0 = *(const uint4*)(Bs + taddr(prow, 8 * g));
            uint4 w1 = *(const uint4*)(Bs + taddr(prow, 8 * g + 4));
            split_frag(w0, w1, bhi[nt], blo[nt]);
        }
        #pragma unroll
        for (int mt = 0; mt < 4; ++mt)
            #pragma unroll
            for (int nt = 0; nt < 4; ++nt) {
                acc[mt][nt] = __builtin_amdgcn_mfma_f32_16x16x32_bf16(ahi[mt], bhi[nt], acc[mt][nt], 0, 0, 0);
                acc[mt][nt] = __builtin_amdgcn_mfma_f32_16x16x32_bf16(ahi[mt], blo[nt], acc[mt][nt], 0, 0, 0);
                acc[mt][nt] = __builtin_amdgcn_mfma_f32_16x16x32_bf16(alo[mt], bhi[nt], acc[mt][nt], 0, 0, 0);
            }
        __syncthreads();
    }

    // ---- epilogue: bias add, store (optionally packed) ----
    #pragma unroll
    for (int mt = 0; mt < 4; ++mt)
        #pragma unroll
        for (int r = 0; r < 4; ++r) {
            int row = m0 + 64 * wm + 16 * mt + 4 * g + r;
            float bb = bias[row];
            #pragma unroll
            for (int nt = 0; nt < 4; ++nt) {
                int col = n0 + 64 * wn + 16 * nt + pl;
                float val = acc[mt][nt][r] + bb;
                long off = ((long)b * M + row) * HW + col;
                if (PACK) ((unsigned*)outv)[off] = pack_hl(val);
                else      ((float*)outv)[off] = val;
            }
        }
}

// ---------------- elementwise ----------------
__global__ __launch_bounds__(256) void pack_arr(const float* __restrict__ src,
                                                unsigned* __restrict__ dst, int n)
{
    int i = blockIdx.x * 256 + threadIdx.x;
    if (i < n) dst[i] = pack_hl(src[i]);
}

// pack one timestep of x: src batch-stride TT*PIX, offset t*PIX applied by caller
__global__ __launch_bounds__(256) void pack_x(const float* __restrict__ x,
                                              unsigned* __restrict__ out)
{
    long i4 = ((long)blockIdx.x * 256 + threadIdx.x) * 4;
    int b = (int)(i4 >> 17);                 // PIX = 2^17
    long off = i4 & (PIX - 1);
    float4 v = *(const float4*)(x + (long)b * TT * PIX + off);
    uint4 o;
    o.x = pack_hl(v.x); o.y = pack_hl(v.y); o.z = pack_hl(v.z); o.w = pack_hl(v.w);
    *(uint4*)(out + i4) = o;
}

// gates fp32 [16][512][1024] -> Cst fp32, Hp packed
__global__ __launch_bounds__(256) void lstm_update(
    const float* __restrict__ gates, float* __restrict__ Cst, unsigned* __restrict__ Hp)
{
    long idx = (long)blockIdx.x * 256 + threadIdx.x;
    int p = idx & 1023;
    int c = (idx >> 10) & 127;
    int b = idx >> 17;
    const float* gb = gates + (long)b * 512 * HW;
    float a  = sigf(gb[(long)c * HW + p]);
    float ga = sigf(gb[(long)(128 + c) * HW + p]);
    float gv = tanhf(gb[(long)(256 + c) * HW + p]);
    float a1 = sigf(gb[(long)(384 + c) * HW + p]);
    float cc = Cst[idx] * a + ga * gv;
    Cst[idx] = cc;
    Hp[idx] = pack_hl(a1 * tanhf(cc));
}

// VKM fp32 [16][640][1024]: vh 0-127, kh 128-255, qh 256-383, km 384-511, vm 512-639
// -> ZHZM packed [16][256][1024]
__global__ __launch_bounds__(256) void attn_kernel(
    const float* __restrict__ VKM, unsigned* __restrict__ ZHZM)
{
    const int j = threadIdx.x & 31;
    const int rloc = threadIdx.x >> 5;
    const int R = blockIdx.x * 8 + rloc;   // over B*C*32
    const int i = R & 31;
    const int c = (R >> 5) & 127;
    const int b = R >> 12;
    const long base = ((long)b * 640 + c) * HW;
    const long obase = ((long)b * 256 + c) * HW;

    float vh  = VKM[base + i * 32 + j];
    float kh  = VKM[base + 128l * HW + i * 32 + j];
    float qhT = VKM[base + 256l * HW + j * 32 + i];
    float km  = VKM[base + 384l * HW + i * 32 + j];
    float vm  = VKM[base + 512l * HW + i * 32 + j];

    float sh = kh * qhT, sm = qhT * km;
    float mh = sh, mm = sm;
    #pragma unroll
    for (int o = 16; o > 0; o >>= 1) {
        mh = fmaxf(mh, __shfl_xor(mh, o, 32));
        mm = fmaxf(mm, __shfl_xor(mm, o, 32));
    }
    float eh = expf(sh - mh), em = expf(sm - mm);
    float s1 = eh, s2 = em;
    #pragma unroll
    for (int o = 16; o > 0; o >>= 1) {
        s1 += __shfl_xor(s1, o, 32);
        s2 += __shfl_xor(s2, o, 32);
    }
    ZHZM[obase + i * 32 + j]            = pack_hl(vh * (eh / s1));
    ZHZM[obase + 128l * HW + i * 32 + j] = pack_hl(vm * (em / s2));
}

// OGI fp32 [16][384][1024] -> mp packed, Hp packed
__global__ __launch_bounds__(256) void final_update(
    const float* __restrict__ ogi, unsigned* __restrict__ mp, unsigned* __restrict__ Hp)
{
    long idx = (long)blockIdx.x * 256 + threadIdx.x;
    int p = idx & 1023;
    int c = (idx >> 10) & 127;
    int b = idx >> 17;
    const float* gb = ogi + (long)b * 384 * HW;
    float ot = sigf(gb[(long)c * HW + p]);
    float gt = tanhf(gb[(long)(128 + c) * HW + p]);
    float it = sigf(gb[(long)(256 + c) * HW + p]);
    float mo = unpack_hl(mp[idx]);
    float mn = gt * it + (1.0f - it) * mo;
    mp[idx] = pack_hl(mn);
    Hp[idx] = pack_hl(ot * mn);
}

__global__ __launch_bounds__(256) void unpack_out(const unsigned* __restrict__ Hp,
                                                  float* __restrict__ out)
{
    long idx = (long)blockIdx.x * 256 + threadIdx.x;
    out[idx] = unpack_hl(Hp[idx]);
}

extern "C" void kernel_launch(void* const* d_in, const int* in_sizes, int n_in,
                              void* d_out, int out_size, void* d_ws, size_t ws_size,
                              hipStream_t stream)
{
    const float* x  = (const float*)d_in[0];   // [16][16][128][1024]
    const float* c0 = (const float*)d_in[1];
    const float* W5 = (const float*)d_in[2];   // [640][128]
    const float* b5 = (const float*)d_in[3];   // [640]
    const float* W8 = (const float*)d_in[4];   // [8][128][256]
    const float* b8 = (const float*)d_in[5];   // [8][128]
    float* out = (float*)d_out;

    const long S = STOT;                        // 2M
    unsigned* Hp  = (unsigned*)d_ws;            // S
    unsigned* mp  = Hp + S;                     // S
    float*    Cst = (float*)(mp + S);           // S
    unsigned* xpt = (unsigned*)(Cst + S);       // S
    unsigned* Wp5 = xpt + S;                    // 81920
    unsigned* Wp8 = Wp5 + 81920;                // 262144
    float*    G1  = (float*)(Wp8 + 262144);     // 4S (shared with OGI 3S)
    float*    OGI = G1;
    float*    VKM = G1 + 4 * S;                 // 5S
    unsigned* ZHZM = (unsigned*)(VKM + 5 * S);  // 2S
    unsigned* Zp  = ZHZM + 2 * S;               // S

    hipMemsetAsync(Hp, 0, S * sizeof(unsigned), stream);
    hipMemsetAsync(mp, 0, S * sizeof(unsigned), stream);
    hipMemcpyAsync(Cst, c0, S * sizeof(float), hipMemcpyDeviceToDevice, stream);

    const dim3 blk(256);
    pack_arr<<<320, blk, 0, stream>>>(W5, Wp5, 81920);
    pack_arr<<<1024, blk, 0, stream>>>(W8, Wp8, 262144);

    const int BIG = 1 << 30;
    for (int t = 0; t < TT; ++t) {
        pack_x<<<2048, blk, 0, stream>>>(x + (long)t * PIX, xpt);

        // gates = W8[4..7] * [H ; x_t]   (M=512, K=256)
        gemm_mfma<false><<<dim3(8, 4, 16), blk, 0, stream>>>(
            Wp8 + 4l * CC * 256, b8 + 4 * CC, Hp, (long)PIX, xpt, (long)PIX,
            128, BIG, G1, 512, 256);
        lstm_update<<<8192, blk, 0, stream>>>(G1, Cst, Hp);

        // vh,kh,qh (from H) + km,vm (from m)   (M=640, K=128)
        gemm_mfma<false><<<dim3(8, 5, 16), blk, 0, stream>>>(
            Wp5, b5, Hp, (long)PIX, mp, (long)PIX,
            128, 384, VKM, 640, 128);

        attn_kernel<<<8192, blk, 0, stream>>>(VKM, ZHZM);

        // z = W8[0] * [zh ; zm]   (M=128, K=256) -> packed
        gemm_mfma<true><<<dim3(8, 1, 16), blk, 0, stream>>>(
            Wp8, b8, ZHZM, 256l * HW, ZHZM, 256l * HW,
            256, BIG, Zp, 128, 256);

        // ot,gt,it = W8[1..3] * [H ; z]   (M=384, K=256)
        gemm_mfma<false><<<dim3(8, 3, 16), blk, 0, stream>>>(
            Wp8 + 1l * CC * 256, b8 + CC, Hp, (long)PIX, Zp, (long)PIX,
            128, BIG, OGI, 384, 256);

        final_update<<<8192, blk, 0, stream>>>(OGI, mp, Hp);
    }

    unpack_out<<<8192, blk, 0, stream>>>(Hp, out);
}

// Round 3
// 1744.881 us; speedup vs baseline: 2.0356x; 1.1384x over previous
//
#include <hip/hip_runtime.h>
#include <hip/hip_bf16.h>

#define BB 16
#define TT 16
#define CC 128
#define HW 1024             // 32*32
#define PIX (CC*HW)         // 131072
#define STOT ((long)BB*PIX) // 2M

typedef short short8 __attribute__((ext_vector_type(8)));
typedef float f32x4  __attribute__((ext_vector_type(4)));

__device__ __forceinline__ float sigf(float x) { return 1.0f / (1.0f + __expf(-x)); }
__device__ __forceinline__ float tanhf_fast(float x) {
    float ax = fabsf(x);
    float t = __expf(-2.0f * ax);
    float r = (1.0f - t) / (1.0f + t);
    return copysignf(r, x);
}

// ---- packed hi/lo bf16: uint32 = (bf16(x)<<16) | bf16(x - bf16(x)) ----
__device__ __forceinline__ unsigned pack_hl(float x) {
    unsigned u = __float_as_uint(x);
    unsigned hi = (u + 0x7fffu + ((u >> 16) & 1u)) >> 16;
    float r = x - __uint_as_float(hi << 16);
    unsigned v = __float_as_uint(r);
    unsigned lo = (v + 0x7fffu + ((v >> 16) & 1u)) >> 16;
    return (hi << 16) | lo;
}
__device__ __forceinline__ float unpack_hl(unsigned p) {
    return __uint_as_float(p & 0xffff0000u) + __uint_as_float(p << 16);
}

__device__ __forceinline__ void split_frag(uint4 a, uint4 b, short8& hi, short8& lo) {
    unsigned w[8] = {a.x, a.y, a.z, a.w, b.x, b.y, b.z, b.w};
    union U { unsigned u[4]; short8 s; } h, l;
    #pragma unroll
    for (int j = 0; j < 4; ++j) {
        h.u[j] = (w[2*j] >> 16)      | (w[2*j+1] & 0xffff0000u);
        l.u[j] = (w[2*j] & 0xffffu)  | (w[2*j+1] << 16);
    }
    hi = h.s; lo = l.s;
}

// LDS tile addr: 128 rows x 32 k-words, stride 36, quad-XOR swizzle
__device__ __forceinline__ int taddr(int row, int kw) {
    return row * 36 + ((((kw >> 2) + (row >> 2)) & 7) << 2) + (kw & 3);
}

// ---------------- MFMA GEMM with fused epilogues ----------------
// MODE 0: fp32 store (+ scalar bias[row])
// MODE 1: packed store (+ scalar bias[row])
// MODE 2: LSTM fuse: rows are c*4+gate; st=Cst(f32), outv=Hp_new(packed)
// MODE 3: final fuse: rows are c*4+gate(3 real+pad); st=mp(packed), outv=Hp_new, Hout optional f32
// B-source: m0>=m_split -> actB(kofs 0); k0>=k_split -> actB(kofs k_split); else actA.
// BF32: actB is fp32 (packed on the fly)
template<int MODE, bool BF32>
__global__ __launch_bounds__(256, 2) void gemm_mfma(
    const unsigned* __restrict__ Wp, const float* __restrict__ bias,
    const unsigned* __restrict__ actA, long sA,
    const void* __restrict__ actBv, long sB,
    int k_split, int m_split,
    void* __restrict__ outv, void* __restrict__ stv, float* __restrict__ Hout,
    int M, int K)
{
    __shared__ __align__(16) unsigned Ws[128 * 36];
    __shared__ __align__(16) unsigned Bs[128 * 36];

    const int b  = blockIdx.z;
    const int n0 = blockIdx.x * 128;
    const int m0 = blockIdx.y * 128;
    const int t  = threadIdx.x;
    const int lane = t & 63;
    const int w  = t >> 6;
    const int wm = w & 1, wn = w >> 1;
    const int g  = lane >> 4, pl = lane & 15;

    f32x4 acc[4][4] = {};

    for (int k0 = 0; k0 < K; k0 += 32) {
        // stage A (weights)
        #pragma unroll
        for (int it = 0; it < 4; ++it) {
            int idx = t + 256 * it;
            int row = idx >> 3, kq = idx & 7;
            uint4 v = *(const uint4*)(Wp + (long)(m0 + row) * K + k0 + 4 * kq);
            *(uint4*)(Ws + taddr(row, 4 * kq)) = v;
        }
        // stage B (activations), register 4x4 transpose
        {
            const int p4 = t & 31, kq = t >> 5;
            const bool useB = (m0 >= m_split) || (k0 >= k_split);
            const int kofs = (m0 >= m_split) ? 0 : k_split;
            uint4 v[4];
            if (BF32 && useB) {
                const float* src = (const float*)actBv + (long)b * sB;
                #pragma unroll
                for (int i = 0; i < 4; ++i) {
                    int kc = k0 + 4 * kq + i - kofs;
                    float4 f = *(const float4*)(src + (long)kc * HW + n0 + 4 * p4);
                    v[i].x = pack_hl(f.x); v[i].y = pack_hl(f.y);
                    v[i].z = pack_hl(f.z); v[i].w = pack_hl(f.w);
                }
            } else {
                const unsigned* src = useB ? ((const unsigned*)actBv + (long)b * sB)
                                           : (actA + (long)b * sA);
                #pragma unroll
                for (int i = 0; i < 4; ++i) {
                    int kc = k0 + 4 * kq + i - (useB ? kofs : 0);
                    v[i] = *(const uint4*)(src + (long)kc * HW + n0 + 4 * p4);
                }
            }
            #pragma unroll
            for (int j = 0; j < 4; ++j) {
                uint4 wv;
                wv.x = ((const unsigned*)&v[0])[j];
                wv.y = ((const unsigned*)&v[1])[j];
                wv.z = ((const unsigned*)&v[2])[j];
                wv.w = ((const unsigned*)&v[3])[j];
                *(uint4*)(Bs + taddr(4 * p4 + j, 4 * kq)) = wv;
            }
        }
        __syncthreads();

        short8 ahi[4], alo[4], bhi[4], blo[4];
        #pragma unroll
        for (int mt = 0; mt < 4; ++mt) {
            int row = 64 * wm + 16 * mt + pl;
            uint4 w0 = *(const uint4*)(Ws + taddr(row, 8 * g));
            uint4 w1 = *(const uint4*)(Ws + taddr(row, 8 * g + 4));
            split_frag(w0, w1, ahi[mt], alo[mt]);
        }
        #pragma unroll
        for (int nt = 0; nt < 4; ++nt) {
            int prow = 64 * wn + 16 * nt + pl;
            uint4 w0 = *(const uint4*)(Bs + taddr(prow, 8 * g));
            uint4 w1 = *(const uint4*)(Bs + taddr(prow, 8 * g + 4));
            split_frag(w0, w1, bhi[nt], blo[nt]);
        }
        #pragma unroll
        for (int mt = 0; mt < 4; ++mt)
            #pragma unroll
            for (int nt = 0; nt < 4; ++nt) {
                acc[mt][nt] = __builtin_amdgcn_mfma_f32_16x16x32_bf16(ahi[mt], bhi[nt], acc[mt][nt], 0, 0, 0);
                acc[mt][nt] = __builtin_amdgcn_mfma_f32_16x16x32_bf16(ahi[mt], blo[nt], acc[mt][nt], 0, 0, 0);
                acc[mt][nt] = __builtin_amdgcn_mfma_f32_16x16x32_bf16(alo[mt], bhi[nt], acc[mt][nt], 0, 0, 0);
            }
        __syncthreads();
    }

    if (MODE <= 1) {
        #pragma unroll
        for (int mt = 0; mt < 4; ++mt)
            #pragma unroll
            for (int r = 0; r < 4; ++r) {
                int row = m0 + 64 * wm + 16 * mt + 4 * g + r;
                float bb = bias[row];
                #pragma unroll
                for (int nt = 0; nt < 4; ++nt) {
                    int col = n0 + 64 * wn + 16 * nt + pl;
                    float val = acc[mt][nt][r] + bb;
                    long off = ((long)b * M + row) * HW + col;
                    if (MODE == 1) ((unsigned*)outv)[off] = pack_hl(val);
                    else           ((float*)outv)[off] = val;
                }
            }
    } else {
        // rows interleaved c*4+gate: one thread's f32x4 = all 4 gates of channel c
        const float4* bias4 = (const float4*)bias;
        unsigned* Hp = (unsigned*)outv;
        #pragma unroll
        for (int mt = 0; mt < 4; ++mt) {
            int c = (m0 >> 2) + 16 * wm + 4 * mt + g;
            float4 bb = bias4[c];
            #pragma unroll
            for (int nt = 0; nt < 4; ++nt) {
                int p = n0 + 64 * wn + 16 * nt + pl;
                long idx = (long)b * PIX + (long)c * HW + p;
                float v0 = acc[mt][nt][0] + bb.x;
                float v1 = acc[mt][nt][1] + bb.y;
                float v2 = acc[mt][nt][2] + bb.z;
                float v3 = acc[mt][nt][3] + bb.w;
                if (MODE == 2) {
                    float* Cst = (float*)stv;
                    float cc = Cst[idx] * sigf(v0) + sigf(v1) * tanhf_fast(v2);
                    Cst[idx] = cc;
                    Hp[idx] = pack_hl(sigf(v3) * tanhf_fast(cc));
                } else {
                    unsigned* mp = (unsigned*)stv;
                    float ot = sigf(v0), gt = tanhf_fast(v1), it = sigf(v2);
                    float mo = unpack_hl(mp[idx]);
                    float mn = gt * it + (1.0f - it) * mo;
                    mp[idx] = pack_hl(mn);
                    float hv = ot * mn;
                    Hp[idx] = pack_hl(hv);
                    if (Hout) Hout[idx] = hv;
                }
            }
        }
    }
}

// ---------------- setup kernels ----------------
__global__ __launch_bounds__(256) void pack_arr(const float* __restrict__ src,
                                                unsigned* __restrict__ dst, int n)
{
    int i = blockIdx.x * 256 + threadIdx.x;
    if (i < n) dst[i] = pack_hl(src[i]);
}

// reorder + pack 4 conv weights into rows c*4+gate; gi0 = first conv index in W8; ngates real gates
__global__ __launch_bounds__(256) void reorder_w8(
    const float* __restrict__ W8, const float* __restrict__ b8,
    unsigned* __restrict__ Wo, float* __restrict__ bo, int gi0, int ngates)
{
    int idx = blockIdx.x * 256 + threadIdx.x;   // over 512*256
    int rr = idx >> 8, k = idx & 255;
    int c = rr >> 2, gg = rr & 3;
    float wv = (gg < ngates) ? W8[((long)(gi0 + gg) * 128 + c) * 256 + k] : 0.0f;
    Wo[idx] = pack_hl(wv);
    if (k == 0) bo[rr] = (gg < ngates) ? b8[(gi0 + gg) * 128 + c] : 0.0f;
}

// ---------------- attention ----------------
// VKM fp32 [16][640][1024]: vh,kh,qh,km,vm. One block per (b,c) 32x32 image.
__global__ __launch_bounds__(1024) void attn_kernel(
    const float* __restrict__ VKM, unsigned* __restrict__ ZHZM)
{
    __shared__ float qs[32 * 33];
    const int tid = threadIdx.x;
    const int b = blockIdx.x >> 7, c = blockIdx.x & 127;
    const long base  = ((long)b * 640 + c) * HW;
    const long obase = ((long)b * 256 + c) * HW;

    qs[(tid >> 5) * 33 + (tid & 31)] = VKM[base + 256l * HW + tid];
    __syncthreads();

    const int i = tid >> 5, j = tid & 31;
    float qhT = qs[j * 33 + i];
    float vh  = VKM[base + tid];
    float kh  = VKM[base + 128l * HW + tid];
    float km  = VKM[base + 384l * HW + tid];
    float vm  = VKM[base + 512l * HW + tid];

    float sh = kh * qhT, sm = qhT * km;
    float mh = sh, mm = sm;
    #pragma unroll
    for (int o = 16; o > 0; o >>= 1) {
        mh = fmaxf(mh, __shfl_xor(mh, o, 32));
        mm = fmaxf(mm, __shfl_xor(mm, o, 32));
    }
    float eh = __expf(sh - mh), em = __expf(sm - mm);
    float s1 = eh, s2 = em;
    #pragma unroll
    for (int o = 16; o > 0; o >>= 1) {
        s1 += __shfl_xor(s1, o, 32);
        s2 += __shfl_xor(s2, o, 32);
    }
    ZHZM[obase + tid]             = pack_hl(vh * (eh / s1));
    ZHZM[obase + 128l * HW + tid] = pack_hl(vm * (em / s2));
}

extern "C" void kernel_launch(void* const* d_in, const int* in_sizes, int n_in,
                              void* d_out, int out_size, void* d_ws, size_t ws_size,
                              hipStream_t stream)
{
    const float* x  = (const float*)d_in[0];   // [16][16][128][1024]
    const float* c0 = (const float*)d_in[1];
    const float* W5 = (const float*)d_in[2];   // [640][128]
    const float* b5 = (const float*)d_in[3];   // [640]
    const float* W8 = (const float*)d_in[4];   // [8][128][256]
    const float* b8 = (const float*)d_in[5];   // [8][128]
    float* out = (float*)d_out;

    const long S = STOT;
    unsigned* Ha   = (unsigned*)d_ws;          // S  (intra-step H)
    unsigned* Hb   = Ha + S;                   // S  (cross-step H)
    unsigned* mp   = Hb + S;                   // S
    float*    Cst  = (float*)(mp + S);         // S
    unsigned* Wp5  = (unsigned*)(Cst + S);     // 81920
    unsigned* Wpz  = Wp5 + 81920;              // 32768
    unsigned* Wg   = Wpz + 32768;              // 131072
    unsigned* Wo   = Wg + 131072;              // 131072
    float*    bg4  = (float*)(Wo + 131072);    // 512
    float*    bo4  = bg4 + 512;                // 512
    float*    VKM  = bo4 + 512;                // 5S fp32
    unsigned* ZHZM = (unsigned*)(VKM + 5 * S); // 2S
    unsigned* Zp   = ZHZM + 2 * S;             // S

    hipMemsetAsync(Hb, 0, S * sizeof(unsigned), stream);
    hipMemsetAsync(mp, 0, S * sizeof(unsigned), stream);
    hipMemcpyAsync(Cst, c0, S * sizeof(float), hipMemcpyDeviceToDevice, stream);

    const dim3 blk(256);
    pack_arr<<<320, blk, 0, stream>>>(W5, Wp5, 81920);
    pack_arr<<<128, blk, 0, stream>>>(W8, Wpz, 32768);
    reorder_w8<<<512, blk, 0, stream>>>(W8, b8, Wg, bg4, 4, 4);
    reorder_w8<<<512, blk, 0, stream>>>(W8, b8, Wo, bo4, 1, 3);

    const int BIG = 1 << 30;
    for (int t = 0; t < TT; ++t) {
        // gates = Wg * [Hb ; x_t], fused LSTM update -> Cst, Ha   (M=512, K=256)
        gemm_mfma<2, true><<<dim3(8, 4, 16), blk, 0, stream>>>(
            Wg, bg4, Hb, (long)PIX, x + (long)t * PIX, (long)TT * PIX,
            128, BIG, Ha, Cst, nullptr, 512, 256);

        // vh,kh,qh (from Ha) + km,vm (from mp)   (M=640, K=128) -> VKM fp32
        gemm_mfma<0, false><<<dim3(8, 5, 16), blk, 0, stream>>>(
            Wp5, b5, Ha, (long)PIX, mp, (long)PIX,
            BIG, 384, VKM, nullptr, nullptr, 640, 128);

        attn_kernel<<<2048, dim3(1024), 0, stream>>>(VKM, ZHZM);

        // z = W8[0] * [zh;zm]   (M=128, K=256) -> packed Zp
        gemm_mfma<1, false><<<dim3(8, 1, 16), blk, 0, stream>>>(
            Wpz, b8, ZHZM, 256l * HW, ZHZM, 256l * HW,
            BIG, BIG, Zp, nullptr, nullptr, 128, 256);

        // o,g,i = Wo * [Ha ; Zp], fused final update -> mp, Hb (+out at t=15)
        gemm_mfma<3, false><<<dim3(8, 4, 16), blk, 0, stream>>>(
            Wo, bo4, Ha, (long)PIX, Zp, (long)PIX,
            128, BIG, Hb, mp, (t == TT - 1) ? out : nullptr, 512, 256);
    }
}

// Round 4
// 1596.608 us; speedup vs baseline: 2.2247x; 1.0929x over previous
//
#include <hip/hip_runtime.h>
#include <hip/hip_bf16.h>

#define BB 16
#define TT 16
#define CC 128
#define HW 1024             // 32*32
#define PIX (CC*HW)         // 131072
#define STOT ((long)BB*PIX) // 2M

typedef short short8 __attribute__((ext_vector_type(8)));
typedef float f32x4  __attribute__((ext_vector_type(4)));

__device__ __forceinline__ float sigf(float x) { return 1.0f / (1.0f + __expf(-x)); }
__device__ __forceinline__ float tanhf_fast(float x) {
    float ax = fabsf(x);
    float t = __expf(-2.0f * ax);
    float r = (1.0f - t) / (1.0f + t);
    return copysignf(r, x);
}

// ---- packed hi/lo bf16: uint32 = (bf16(x)<<16) | bf16(x - bf16(x)) ----
__device__ __forceinline__ unsigned pack_hl(float x) {
    unsigned u = __float_as_uint(x);
    unsigned hi = (u + 0x7fffu + ((u >> 16) & 1u)) >> 16;
    float r = x - __uint_as_float(hi << 16);
    unsigned v = __float_as_uint(r);
    unsigned lo = (v + 0x7fffu + ((v >> 16) & 1u)) >> 16;
    return (hi << 16) | lo;
}
__device__ __forceinline__ float unpack_hl(unsigned p) {
    return __uint_as_float(p & 0xffff0000u) + __uint_as_float(p << 16);
}

__device__ __forceinline__ void split_frag(uint4 a, uint4 b, short8& hi, short8& lo) {
    unsigned w[8] = {a.x, a.y, a.z, a.w, b.x, b.y, b.z, b.w};
    union U { unsigned u[4]; short8 s; } h, l;
    #pragma unroll
    for (int j = 0; j < 4; ++j) {
        h.u[j] = (w[2*j] >> 16)      | (w[2*j+1] & 0xffff0000u);
        l.u[j] = (w[2*j] & 0xffffu)  | (w[2*j+1] << 16);
    }
    hi = h.s; lo = l.s;
}

// LDS tile addr: 128 rows x 32 k-words, stride 36, quad-XOR swizzle
__device__ __forceinline__ int taddr(int row, int kw) {
    return row * 36 + ((((kw >> 2) + (row >> 2)) & 7) << 2) + (kw & 3);
}

// ---------------- MFMA GEMM with fused epilogues ----------------
// MODE 0: fp32 store (+ scalar bias[row])
// MODE 2: LSTM fuse: rows c*4+gate; st=Cst(f32), outv=Hp_new(packed)
// MODE 3: final fuse: rows c*4+gate(3 real+pad); st=mp(packed), outv=Hp_new, Hout optional f32
// B-source: m0>=m_split -> actB(kofs 0); k0>=k_split -> actB(kofs k_split); else actA.
// BF32: actB is fp32 (packed on the fly)
template<int MODE, bool BF32>
__global__ __launch_bounds__(256, 2) void gemm_mfma(
    const unsigned* __restrict__ Wp, const float* __restrict__ bias,
    const unsigned* __restrict__ actA, long sA,
    const void* __restrict__ actBv, long sB,
    int k_split, int m_split,
    void* __restrict__ outv, void* __restrict__ stv, float* __restrict__ Hout,
    int M, int K)
{
    __shared__ __align__(16) unsigned Ws[128 * 36];
    __shared__ __align__(16) unsigned Bs[128 * 36];

    const int b  = blockIdx.z;
    const int n0 = blockIdx.x * 128;
    const int m0 = blockIdx.y * 128;
    const int t  = threadIdx.x;
    const int lane = t & 63;
    const int w  = t >> 6;
    const int wm = w & 1, wn = w >> 1;
    const int g  = lane >> 4, pl = lane & 15;

    f32x4 acc[4][4] = {};

    for (int k0 = 0; k0 < K; k0 += 32) {
        // stage A (weights)
        #pragma unroll
        for (int it = 0; it < 4; ++it) {
            int idx = t + 256 * it;
            int row = idx >> 3, kq = idx & 7;
            uint4 v = *(const uint4*)(Wp + (long)(m0 + row) * K + k0 + 4 * kq);
            *(uint4*)(Ws + taddr(row, 4 * kq)) = v;
        }
        // stage B (activations), register 4x4 transpose
        {
            const int p4 = t & 31, kq = t >> 5;
            const bool useB = (m0 >= m_split) || (k0 >= k_split);
            const int kofs = (m0 >= m_split) ? 0 : k_split;
            uint4 v[4];
            if (BF32 && useB) {
                const float* src = (const float*)actBv + (long)b * sB;
                #pragma unroll
                for (int i = 0; i < 4; ++i) {
                    int kc = k0 + 4 * kq + i - kofs;
                    float4 f = *(const float4*)(src + (long)kc * HW + n0 + 4 * p4);
                    v[i].x = pack_hl(f.x); v[i].y = pack_hl(f.y);
                    v[i].z = pack_hl(f.z); v[i].w = pack_hl(f.w);
                }
            } else {
                const unsigned* src = useB ? ((const unsigned*)actBv + (long)b * sB)
                                           : (actA + (long)b * sA);
                #pragma unroll
                for (int i = 0; i < 4; ++i) {
                    int kc = k0 + 4 * kq + i - (useB ? kofs : 0);
                    v[i] = *(const uint4*)(src + (long)kc * HW + n0 + 4 * p4);
                }
            }
            #pragma unroll
            for (int j = 0; j < 4; ++j) {
                uint4 wv;
                wv.x = ((const unsigned*)&v[0])[j];
                wv.y = ((const unsigned*)&v[1])[j];
                wv.z = ((const unsigned*)&v[2])[j];
                wv.w = ((const unsigned*)&v[3])[j];
                *(uint4*)(Bs + taddr(4 * p4 + j, 4 * kq)) = wv;
            }
        }
        __syncthreads();

        short8 ahi[4], alo[4], bhi[4], blo[4];
        #pragma unroll
        for (int mt = 0; mt < 4; ++mt) {
            int row = 64 * wm + 16 * mt + pl;
            uint4 w0 = *(const uint4*)(Ws + taddr(row, 8 * g));
            uint4 w1 = *(const uint4*)(Ws + taddr(row, 8 * g + 4));
            split_frag(w0, w1, ahi[mt], alo[mt]);
        }
        #pragma unroll
        for (int nt = 0; nt < 4; ++nt) {
            int prow = 64 * wn + 16 * nt + pl;
            uint4 w0 = *(const uint4*)(Bs + taddr(prow, 8 * g));
            uint4 w1 = *(const uint4*)(Bs + taddr(prow, 8 * g + 4));
            split_frag(w0, w1, bhi[nt], blo[nt]);
        }
        #pragma unroll
        for (int mt = 0; mt < 4; ++mt)
            #pragma unroll
            for (int nt = 0; nt < 4; ++nt) {
                acc[mt][nt] = __builtin_amdgcn_mfma_f32_16x16x32_bf16(ahi[mt], bhi[nt], acc[mt][nt], 0, 0, 0);
                acc[mt][nt] = __builtin_amdgcn_mfma_f32_16x16x32_bf16(ahi[mt], blo[nt], acc[mt][nt], 0, 0, 0);
                acc[mt][nt] = __builtin_amdgcn_mfma_f32_16x16x32_bf16(alo[mt], bhi[nt], acc[mt][nt], 0, 0, 0);
            }
        __syncthreads();
    }

    if (MODE == 0) {
        #pragma unroll
        for (int mt = 0; mt < 4; ++mt)
            #pragma unroll
            for (int r = 0; r < 4; ++r) {
                int row = m0 + 64 * wm + 16 * mt + 4 * g + r;
                float bb = bias[row];
                #pragma unroll
                for (int nt = 0; nt < 4; ++nt) {
                    int col = n0 + 64 * wn + 16 * nt + pl;
                    ((float*)outv)[((long)b * M + row) * HW + col] = acc[mt][nt][r] + bb;
                }
            }
    } else {
        // rows interleaved c*4+gate: one thread's f32x4 = all 4 gates of channel c
        const float4* bias4 = (const float4*)bias;
        unsigned* Hp = (unsigned*)outv;
        #pragma unroll
        for (int mt = 0; mt < 4; ++mt) {
            int c = (m0 >> 2) + 16 * wm + 4 * mt + g;
            float4 bb = bias4[c];
            #pragma unroll
            for (int nt = 0; nt < 4; ++nt) {
                int p = n0 + 64 * wn + 16 * nt + pl;
                long idx = (long)b * PIX + (long)c * HW + p;
                float v0 = acc[mt][nt][0] + bb.x;
                float v1 = acc[mt][nt][1] + bb.y;
                float v2 = acc[mt][nt][2] + bb.z;
                float v3 = acc[mt][nt][3] + bb.w;
                if (MODE == 2) {
                    float* Cst = (float*)stv;
                    float cc = Cst[idx] * sigf(v0) + sigf(v1) * tanhf_fast(v2);
                    Cst[idx] = cc;
                    Hp[idx] = pack_hl(sigf(v3) * tanhf_fast(cc));
                } else {
                    unsigned* mp = (unsigned*)stv;
                    float ot = sigf(v0), gt = tanhf_fast(v1), it = sigf(v2);
                    float mo = unpack_hl(mp[idx]);
                    float mn = gt * it + (1.0f - it) * mo;
                    mp[idx] = pack_hl(mn);
                    float hv = ot * mn;
                    Hp[idx] = pack_hl(hv);
                    if (Hout) Hout[idx] = hv;
                }
            }
        }
    }
}

// ---------------- setup kernels ----------------
__global__ __launch_bounds__(256) void pack_arr(const float* __restrict__ src,
                                                unsigned* __restrict__ dst, int n)
{
    int i = blockIdx.x * 256 + threadIdx.x;
    if (i < n) dst[i] = pack_hl(src[i]);
}

// gates weights: rows c*4+gate, convs 10..13 (W8[4..7]), K=256
__global__ __launch_bounds__(256) void reorder_w8(
    const float* __restrict__ W8, const float* __restrict__ b8,
    unsigned* __restrict__ Wo, float* __restrict__ bo, int gi0, int ngates)
{
    int idx = blockIdx.x * 256 + threadIdx.x;   // over 512*256
    int rr = idx >> 8, k = idx & 255;
    int c = rr >> 2, gg = rr & 3;
    float wv = (gg < ngates) ? W8[((long)(gi0 + gg) * 128 + c) * 256 + k] : 0.0f;
    Wo[idx] = pack_hl(wv);
    if (k == 0) bo[rr] = (gg < ngates) ? b8[(gi0 + gg) * 128 + c] : 0.0f;
}

// composite o/g/i weights: rows c*4+gate (convs 7/8/9 = W8[1..3], gate 3 = pad), K=384.
// cols 0..127: H part.  cols 128..383: (Wo_z @ Wz) over [zh;zm]  (conv6 folded in).
// bias: b_ogi + Wo_z @ bz.
__global__ __launch_bounds__(256) void build_wo(
    const float* __restrict__ W8, const float* __restrict__ b8,
    unsigned* __restrict__ Wo, float* __restrict__ bo)
{
    int idx = blockIdx.x * 256 + threadIdx.x;   // over 512*384
    if (idx >= 512 * 384) return;
    int rr = idx / 384, k = idx - rr * 384;
    int c = rr >> 2, gg = rr & 3;
    float wv = 0.0f;
    if (gg < 3) {
        const float* wr = W8 + ((long)(1 + gg) * 128 + c) * 256;
        if (k < 128) {
            wv = wr[k];
        } else {
            int i = k - 128;
            float s = 0.0f;
            for (int j = 0; j < 128; ++j)
                s += wr[128 + j] * W8[(long)j * 256 + i];   // Wz = W8[0]
            wv = s;
        }
    }
    Wo[(long)rr * 384 + k] = pack_hl(wv);
    if (k == 0) {
        float bb = 0.0f;
        if (gg < 3) {
            bb = b8[(1 + gg) * 128 + c];
            const float* wr = W8 + ((long)(1 + gg) * 128 + c) * 256;
            for (int j = 0; j < 128; ++j) bb += wr[128 + j] * b8[j];  // bz = b8[0]
        }
        bo[rr] = bb;
    }
}

// ---------------- attention ----------------
// VKM fp32 [16][640][1024]: vh,kh,qh,km,vm. One block per (b,c) 32x32 image.
__global__ __launch_bounds__(1024) void attn_kernel(
    const float* __restrict__ VKM, unsigned* __restrict__ ZHZM)
{
    __shared__ float qs[32 * 33];
    const int tid = threadIdx.x;
    const int b = blockIdx.x >> 7, c = blockIdx.x & 127;
    const long base  = ((long)b * 640 + c) * HW;
    const long obase = ((long)b * 256 + c) * HW;

    qs[(tid >> 5) * 33 + (tid & 31)] = VKM[base + 256l * HW + tid];
    __syncthreads();

    const int i = tid >> 5, j = tid & 31;
    float qhT = qs[j * 33 + i];
    float vh  = VKM[base + tid];
    float kh  = VKM[base + 128l * HW + tid];
    float km  = VKM[base + 384l * HW + tid];
    float vm  = VKM[base + 512l * HW + tid];

    float sh = kh * qhT, sm = qhT * km;
    float mh = sh, mm = sm;
    #pragma unroll
    for (int o = 16; o > 0; o >>= 1) {
        mh = fmaxf(mh, __shfl_xor(mh, o, 32));
        mm = fmaxf(mm, __shfl_xor(mm, o, 32));
    }
    float eh = __expf(sh - mh), em = __expf(sm - mm);
    float s1 = eh, s2 = em;
    #pragma unroll
    for (int o = 16; o > 0; o >>= 1) {
        s1 += __shfl_xor(s1, o, 32);
        s2 += __shfl_xor(s2, o, 32);
    }
    ZHZM[obase + tid]             = pack_hl(vh * (eh / s1));
    ZHZM[obase + 128l * HW + tid] = pack_hl(vm * (em / s2));
}

extern "C" void kernel_launch(void* const* d_in, const int* in_sizes, int n_in,
                              void* d_out, int out_size, void* d_ws, size_t ws_size,
                              hipStream_t stream)
{
    const float* x  = (const float*)d_in[0];   // [16][16][128][1024]
    const float* c0 = (const float*)d_in[1];
    const float* W5 = (const float*)d_in[2];   // [640][128]
    const float* b5 = (const float*)d_in[3];   // [640]
    const float* W8 = (const float*)d_in[4];   // [8][128][256]
    const float* b8 = (const float*)d_in[5];   // [8][128]
    float* out = (float*)d_out;

    const long S = STOT;
    unsigned* Ha   = (unsigned*)d_ws;          // S  (intra-step H)
    unsigned* Hb   = Ha + S;                   // S  (cross-step H)
    unsigned* mp   = Hb + S;                   // S
    float*    Cst  = (float*)(mp + S);         // S
    unsigned* Wp5  = (unsigned*)(Cst + S);     // 81920
    unsigned* Wg   = Wp5 + 81920;              // 131072
    unsigned* Wo   = Wg + 131072;              // 196608 (512x384)
    float*    bg4  = (float*)(Wo + 196608);    // 512
    float*    bo4  = bg4 + 512;                // 512
    float*    VKM  = bo4 + 512;                // 5S fp32
    unsigned* ZHZM = (unsigned*)(VKM + 5 * S); // 2S

    hipMemsetAsync(Hb, 0, S * sizeof(unsigned), stream);
    hipMemsetAsync(mp, 0, S * sizeof(unsigned), stream);
    hipMemcpyAsync(Cst, c0, S * sizeof(float), hipMemcpyDeviceToDevice, stream);

    const dim3 blk(256);
    pack_arr<<<320, blk, 0, stream>>>(W5, Wp5, 81920);
    reorder_w8<<<512, blk, 0, stream>>>(W8, b8, Wg, bg4, 4, 4);
    build_wo<<<768, blk, 0, stream>>>(W8, b8, Wo, bo4);

    const int BIG = 1 << 30;
    for (int t = 0; t < TT; ++t) {
        // gates = Wg * [Hb ; x_t], fused LSTM -> Cst, Ha   (M=512, K=256)
        gemm_mfma<2, true><<<dim3(8, 4, 16), blk, 0, stream>>>(
            Wg, bg4, Hb, (long)PIX, x + (long)t * PIX, (long)TT * PIX,
            128, BIG, Ha, Cst, nullptr, 512, 256);

        // vh,kh,qh (from Ha) + km,vm (from mp)   (M=640, K=128) -> VKM fp32
        gemm_mfma<0, false><<<dim3(8, 5, 16), blk, 0, stream>>>(
            Wp5, b5, Ha, (long)PIX, mp, (long)PIX,
            BIG, 384, VKM, nullptr, nullptr, 640, 128);

        attn_kernel<<<2048, dim3(1024), 0, stream>>>(VKM, ZHZM);

        // o,g,i = Wo * [Ha ; ZHZM] (conv6 folded), fused final -> mp, Hb (+out at t=15)
        // (M=512, K=384)
        gemm_mfma<3, false><<<dim3(8, 4, 16), blk, 0, stream>>>(
            Wo, bo4, Ha, (long)PIX, ZHZM, 2l * PIX,
            128, BIG, Hb, mp, (t == TT - 1) ? out : nullptr, 512, 384);
    }
}